// Round 11
// baseline (36.868 us; speedup 1.0000x reference)
//
#include <hip/hip_runtime.h>

// CARAFE: x [4,256,64,64] f32, kernel [4,25,128,128] f32 -> out [4,256,128,128] f32
// out[b,c,2h+p,2w+q] = sum_{ki,kj} x[b,c,h+ki-2,w+kj-2] * kern[b,ki*5+kj,2h+p,2w+q]
//
// R10 decisive test: NO LDS, NO barrier (R7/R8/R9 all ~30us despite varying
// occupancy 2x, x-load count 2x, store order -> shared suspect = weight-LDS
// stage+barrier+ds_read pipe). Weights now per-tap aligned v4 global loads:
// the 25.6KB per-(b,h) slab is L1-resident, shared by 8 waves/block and the
// 8 co-XCD cc-blocks. x: 3 aligned v2 per (ch,row) serving all 5 kj from regs
// (R6 lesson: NEVER per-tap scalar x loads). Plain v4 stores (R6: NT 8B stores
// = 17x ECC-RMW). cc-fast XCD-chunked mapping (R9 showed h-fast slightly worse).

typedef float v2 __attribute__((ext_vector_type(2)));
typedef float v4 __attribute__((ext_vector_type(4)));

__global__ __launch_bounds__(256, 4)
void carafe_kernel(const float* __restrict__ x,
                   const float* __restrict__ kern,
                   float* __restrict__ out) {
    // XCD-chunked swizzle: 2048 blocks, 256 per XCD (cc fast within an XCD chunk).
    const int raw = blockIdx.x;
    const int l   = (raw & 7) * 256 + (raw >> 3);
    const int cc  = l & 7;           // 32-channel chunk
    const int h   = (l >> 3) & 63;   // input row
    const int b   = l >> 9;          // batch
    const int tid = threadIdx.x;
    const int t   = tid & 31;        // col group: input cols 2t, 2t+1 -> out 4t..4t+3
    const int g   = tid >> 5;        // ch group: 4 channels
    const int c0  = cc * 32 + g * 4;

    float acc[4][2][2][2] = {};      // [ch][cj][p][q]
    const float* xb = x + (size_t)(b * 256 + c0) * 4096;
    // weight base for this thread's 4 output cols: kern[b, k, 2h+p, 4t..4t+3]
    const float* kb = kern + (size_t)b * 25 * 16384 + (size_t)(2 * h) * 128 + 4 * t;

#pragma unroll
    for (int ki = 0; ki < 5; ++ki) {
        const int gr = h + ki - 2;
        if ((unsigned)gr >= 64u) continue;     // block-uniform zero-pad rows

        // x window per ch: cols 2t-2 .. 2t+3 via 3 aligned v2 loads
        float xw[4][6];
#pragma unroll
        for (int ch = 0; ch < 4; ++ch) {
            const float* rowp = xb + (size_t)ch * 4096 + gr * 64;
            const v2 A = *(const v2*)(rowp + (t ? 2 * t - 2 : 0));
            const v2 B = *(const v2*)(rowp + 2 * t);
            const v2 C = *(const v2*)(rowp + (t < 31 ? 2 * t + 2 : 60));
            xw[ch][0] = t ? A.x : 0.0f;            // col 2t-2
            xw[ch][1] = t ? A.y : 0.0f;            // col 2t-1
            xw[ch][2] = B.x;  xw[ch][3] = B.y;     // cols 2t, 2t+1
            xw[ch][4] = (t < 31) ? C.x : 0.0f;     // col 2t+2
            xw[ch][5] = (t < 31) ? C.y : 0.0f;     // col 2t+3
        }

#pragma unroll
        for (int kj = 0; kj < 5; ++kj) {
            const int k = ki * 5 + kj;
            // weights from global (L1-resident slab): 2 aligned v4 per tap
            const v4 w0 = *(const v4*)(kb + (size_t)k * 16384);        // p=0
            const v4 w1 = *(const v4*)(kb + (size_t)k * 16384 + 128);  // p=1
#pragma unroll
            for (int ch = 0; ch < 4; ++ch) {
#pragma unroll
                for (int cj = 0; cj < 2; ++cj) {
                    const float xv = xw[ch][cj + kj];
                    acc[ch][cj][0][0] += w0[2 * cj]     * xv;
                    acc[ch][cj][0][1] += w0[2 * cj + 1] * xv;
                    acc[ch][cj][1][0] += w1[2 * cj]     * xv;
                    acc[ch][cj][1][1] += w1[2 * cj + 1] * xv;
                }
            }
        }
    }

    // ---- stores: 1 v4 per (ch,p); lanes t=0..31 cover a contiguous 512B row ----
#pragma unroll
    for (int ch = 0; ch < 4; ++ch) {
        float* ob = out + ((size_t)(b * 256 + c0 + ch) * 128 + 2 * h) * 128 + 4 * t;
#pragma unroll
        for (int p = 0; p < 2; ++p) {
            v4 s;
            s.x = acc[ch][0][p][0]; s.y = acc[ch][0][p][1];
            s.z = acc[ch][1][p][0]; s.w = acc[ch][1][p][1];
            *(v4*)(ob + p * 128) = s;
        }
    }
}

extern "C" void kernel_launch(void* const* d_in, const int* in_sizes, int n_in,
                              void* d_out, int out_size, void* d_ws, size_t ws_size,
                              hipStream_t stream) {
    const float* x    = (const float*)d_in[0];
    const float* kern = (const float*)d_in[1];
    float* out        = (float*)d_out;
    // grid: b(4) * h(64) * cc(8) = 2048 blocks of 256 threads
    carafe_kernel<<<dim3(2048), dim3(256), 0, stream>>>(x, kern, out);
}

// Round 12
// 30.070 us; speedup vs baseline: 1.2261x; 1.2261x over previous
//
#include <hip/hip_runtime.h>

// CARAFE: x [4,256,64,64] f32, kernel [4,25,128,128] f32 -> out [4,256,128,128] f32
// out[b,c,2h+p,2w+q] = sum_{ki,kj} x[b,c,h+ki-2,w+kj-2] * kern[b,ki*5+kj,2h+p,2w+q]
//
// R12: amortize weight ds_reads over 2x channels. Ledger: R8 (LDS wt, 4ch) 29.3us;
// R10 (no LDS) 36.9us -> ds_read beats L1 for weights; occupancy/store-order ~0.
// R8 model: weight-LDS pipe 14.7us dominates (every wave reads the whole 25.6KB
// slab; only 4ch amortization). Here 8ch x 2col per thread: same 2 ds_read_b128
// per tap per wave now serve 64 FMA -> LDS pipe ~8us, under the ~14us HBM floor.
// Keep: plain v4 stores (R6: NT sub-line stores = 17x ECC-RMW), cc-fast XCD
// chunking, 3x aligned-v2 x windows, block-uniform edge-row skip.

typedef float v2 __attribute__((ext_vector_type(2)));
typedef float v4 __attribute__((ext_vector_type(4)));

__global__ __launch_bounds__(256, 2)
void carafe_kernel(const float* __restrict__ x,
                   const float* __restrict__ kern,
                   float* __restrict__ out) {
    __shared__ __align__(16) float wt[25 * 256];   // [k][p][ow] for rows {2h,2h+1}

    // XCD-chunked swizzle: 1024 blocks, 128 per XCD (cc fast within a chunk).
    const int raw = blockIdx.x;
    const int l   = (raw & 7) * 128 + (raw >> 3);
    const int cc  = l & 3;           // 64-channel chunk
    const int h   = (l >> 2) & 63;   // input row
    const int b   = l >> 8;          // batch
    const int tid = threadIdx.x;
    const int t   = tid & 31;        // col group: input cols 2t,2t+1 -> out 4t..4t+3
    const int g   = tid >> 5;        // ch group: 8 channels
    const int c0  = cc * 64 + g * 8;

    // ---- stage weights (25.6KB) as v4: 1600 v4 loads, coalesced ----
    {
        const float* kbase = kern + (size_t)b * 25 * 16384 + (size_t)(2 * h) * 128;
        for (int idx = tid; idx < 1600; idx += 256) {
            const int f  = idx * 4;          // flat float index in wt
            const int k  = f >> 8;
            const int r  = f & 255;          // p*128 + ow
            *(v4*)&wt[f] = *(const v4*)(kbase + (size_t)k * 16384 + r);
        }
    }
    __syncthreads();

    float acc[8][2][2][2] = {};      // [ch][cj][p][q]
    const float* xb = x + (size_t)(b * 256 + c0) * 4096;

#pragma unroll
    for (int ki = 0; ki < 5; ++ki) {
        const int gr = h + ki - 2;
        if ((unsigned)gr >= 64u) continue;     // block-uniform zero-pad rows

        // x window per ch: cols 2t-2 .. 2t+3 via 3 aligned v2 loads
        float xw[8][6];
#pragma unroll
        for (int ch = 0; ch < 8; ++ch) {
            const float* rowp = xb + (size_t)ch * 4096 + gr * 64;
            const v2 A = *(const v2*)(rowp + (t ? 2 * t - 2 : 0));
            const v2 B = *(const v2*)(rowp + 2 * t);
            const v2 C = *(const v2*)(rowp + (t < 31 ? 2 * t + 2 : 60));
            xw[ch][0] = t ? A.x : 0.0f;            // col 2t-2
            xw[ch][1] = t ? A.y : 0.0f;            // col 2t-1
            xw[ch][2] = B.x;  xw[ch][3] = B.y;     // cols 2t, 2t+1
            xw[ch][4] = (t < 31) ? C.x : 0.0f;     // col 2t+2
            xw[ch][5] = (t < 31) ? C.y : 0.0f;     // col 2t+3
        }

#pragma unroll
        for (int kj = 0; kj < 5; ++kj) {
            const int k = ki * 5 + kj;
            const v4 w0 = *(const v4*)&wt[k * 256 + 4 * t];        // p=0, ow 4t..4t+3
            const v4 w1 = *(const v4*)&wt[k * 256 + 128 + 4 * t];  // p=1
#pragma unroll
            for (int ch = 0; ch < 8; ++ch) {
#pragma unroll
                for (int cj = 0; cj < 2; ++cj) {
                    const float xv = xw[ch][cj + kj];
                    acc[ch][cj][0][0] += w0[2 * cj]     * xv;
                    acc[ch][cj][0][1] += w0[2 * cj + 1] * xv;
                    acc[ch][cj][1][0] += w1[2 * cj]     * xv;
                    acc[ch][cj][1][1] += w1[2 * cj + 1] * xv;
                }
            }
        }
    }

    // ---- stores: 1 v4 per (ch,p); lanes t=0..31 cover a contiguous 512B row ----
#pragma unroll
    for (int ch = 0; ch < 8; ++ch) {
        float* ob = out + ((size_t)(b * 256 + c0 + ch) * 128 + 2 * h) * 128 + 4 * t;
#pragma unroll
        for (int p = 0; p < 2; ++p) {
            v4 s;
            s.x = acc[ch][0][p][0]; s.y = acc[ch][0][p][1];
            s.z = acc[ch][1][p][0]; s.w = acc[ch][1][p][1];
            *(v4*)(ob + p * 128) = s;
        }
    }
}

extern "C" void kernel_launch(void* const* d_in, const int* in_sizes, int n_in,
                              void* d_out, int out_size, void* d_ws, size_t ws_size,
                              hipStream_t stream) {
    const float* x    = (const float*)d_in[0];
    const float* kern = (const float*)d_in[1];
    float* out        = (float*)d_out;
    // grid: b(4) * h(64) * cc(4) = 1024 blocks of 256 threads
    carafe_kernel<<<dim3(1024), dim3(256), 0, stream>>>(x, kern, out);
}